// Round 12
// baseline (384.842 us; speedup 1.0000x reference)
//
#include <hip/hip_runtime.h>
#include <hip/hip_bf16.h>

// Problem constants
#define BB 8
#define NN 1024
#define BN 8192       // B*N
#define DD 256
#define HEADS 4
#define HD 1024       // HEADS*D
#define DSS 768
#define DTT 128
#define NE 131072     // raw edges
#define DEGC 128      // padded CSR slots per node (max in-degree ~41 incl. self-loop)

typedef __hip_bfloat16 bf16;
typedef __attribute__((ext_vector_type(8))) short short8;   // 8 bf16 (4 VGPRs)
typedef __attribute__((ext_vector_type(4))) float floatx4;  // MFMA C/D

__device__ __forceinline__ float toF(bf16 x){ return __bfloat162float(x); }
__device__ __forceinline__ void stC(float* p, float v){ *p = v; }
__device__ __forceinline__ void stC(bf16* p, float v){ *p = __float2bfloat16(v); }
__device__ __forceinline__ float bf_lo(unsigned u){ return __uint_as_float(u << 16); }
__device__ __forceinline__ float bf_hi(unsigned u){ return __uint_as_float(u & 0xffff0000u); }

__device__ __forceinline__ uint4 pk8(float4 a, float4 b){
  bf16 t[8] = {__float2bfloat16(a.x),__float2bfloat16(a.y),__float2bfloat16(a.z),__float2bfloat16(a.w),
               __float2bfloat16(b.x),__float2bfloat16(b.y),__float2bfloat16(b.z),__float2bfloat16(b.w)};
  return *(uint4*)t;
}
__device__ __forceinline__ float4 combf(float4 a, float4 t, float4 e, float4 m, float p0, float p1){
  a.x += p0*t.x + p1*e.x + m.x;
  a.y += p0*t.y + p1*e.y + m.y;
  a.z += p0*t.z + p1*e.z + m.z;
  a.w += p0*t.w + p1*e.w + m.w;
  return a;
}

__device__ __forceinline__ float wredsum(float v){
  #pragma unroll
  for (int off = 32; off; off >>= 1) v += __shfl_xor(v, off);
  return v;
}
__device__ __forceinline__ float wredmax(float v){
  #pragma unroll
  for (int off = 32; off; off >>= 1) v = fmaxf(v, __shfl_xor(v, off));
  return v;
}

// transpose one 32x32 tile: dst[c][r] = bf16(src[r][c]) (whole block same branch)
__device__ __forceinline__ void dev_transpose(
    float tb[32][33], const float* __restrict__ src, bf16* __restrict__ dst,
    int R, int C, int bx, int by, int tid)
{
  int c0 = bx*32, r0 = by*32;
  int tr = tid >> 5, tc = tid & 31;
  #pragma unroll
  for (int i = 0; i < 4; i++)
    tb[tr + i*8][tc] = src[(size_t)(r0 + tr + i*8)*C + c0 + tc];
  __syncthreads();
  #pragma unroll
  for (int i = 0; i < 4; i++)
    dst[(size_t)(c0 + tr + i*8)*R + r0 + tc] = __float2bfloat16(tb[tc][tr + i*8]);
}

// per-head transpose: dst[c][h*256+d] = src[d][h*256+c]  (src,dst both stride HD)
__device__ __forceinline__ void dev_transpose_head(
    float tb[32][33], const float* __restrict__ src, bf16* __restrict__ dst,
    int h, int bx, int by, int tid)
{
  int c0 = bx*32, r0 = by*32;
  int tr = tid >> 5, tc = tid & 31;
  #pragma unroll
  for (int i = 0; i < 4; i++)
    tb[tr + i*8][tc] = src[(size_t)(r0 + tr + i*8)*HD + h*DD + c0 + tc];
  __syncthreads();
  #pragma unroll
  for (int i = 0; i < 4; i++)
    dst[(size_t)(c0 + tr + i*8)*HD + h*DD + r0 + tc] = __float2bfloat16(tb[tc][tr + i*8]);
}

// ---------------------------------------------------------------------------
// prep1: ALL independent prep work in one launch, partitioned by block range.
//  [0,32)    textf/editp projections
//  [32,128)  WfullT (ws@wp fused weight, transposed bf16)
//  [128,160) Wcv = iw_v^T @ ow^T (+ bcv)
//  [160,416) g1_lin per-head transpose -> g1R
//  [416,672) g2_lin per-head transpose -> g2R
//  [672,736) cw1 transpose -> W2T[0:256]
//  [736,800) aw1 transpose -> W2T[256:512]
//  [800,928) WdT block-diag final weight + bias23
//  [928,960) padded-CSR init + zero a_s/a_d + s0b/s1b + bias2
// ---------------------------------------------------------------------------
__global__ __launch_bounds__(256) void prep1(
    const float* __restrict__ text_emb, const float* __restrict__ edit_emb,
    const float* __restrict__ wt, const float* __restrict__ bt,
    const float* __restrict__ we, const float* __restrict__ be,
    float* __restrict__ textf, float* __restrict__ editp,
    const float* __restrict__ wsm, const float* __restrict__ wp, bf16* __restrict__ WfT,
    const float* __restrict__ mha_iw, const float* __restrict__ mha_ib,
    const float* __restrict__ mha_ow, const float* __restrict__ mha_ob,
    float* __restrict__ Wcv, float* __restrict__ bcv,
    const float* __restrict__ g1_lin, bf16* __restrict__ g1R,
    const float* __restrict__ g2_lin, bf16* __restrict__ g2R,
    const float* __restrict__ cw1, const float* __restrict__ aw1, bf16* __restrict__ W2T,
    const float* __restrict__ cw2, const float* __restrict__ cb2,
    const float* __restrict__ aw2, const float* __restrict__ ab2,
    bf16* __restrict__ WdT, float* __restrict__ bias23,
    int* __restrict__ counts, int* __restrict__ csr, float* __restrict__ zz,
    float* __restrict__ s0b, float* __restrict__ s1b,
    const float* __restrict__ cb1, const float* __restrict__ ab1, float* __restrict__ bias2)
{
  __shared__ float tpose[32][33];
  __shared__ float red[2][4][64];
  int blk = blockIdx.x, tid = threadIdx.x;
  if (blk < 32) {
    int b = blk & 7, l = tid & 63, qq = tid >> 6;
    int d = (blk >> 3)*64 + l;
    float tf = 0.f;
    for (int k = qq*32; k < qq*32 + 32; k++) tf += text_emb[b*DTT + k] * wt[(size_t)k*DD + d];
    float ep = 0.f;
    for (int k = qq*192; k < qq*192 + 192; k++) ep += edit_emb[b*DSS + k] * we[(size_t)k*DD + d];
    red[0][qq][l] = tf; red[1][qq][l] = ep;
    __syncthreads();
    if (tid < 64) {
      int dd = (blk >> 3)*64 + tid;
      textf[b*DD + dd] = red[0][0][tid]+red[0][1][tid]+red[0][2][tid]+red[0][3][tid] + bt[dd];
      editp[b*DD + dd] = red[1][0][tid]+red[1][1][tid]+red[1][2][tid]+red[1][3][tid] + be[dd];
    }
  } else if (blk < 128) {
    int k0 = (blk - 32)*8, d = tid;
    float acc[8] = {};
    for (int j = 0; j < DD; j++) {
      float wv = wp[(size_t)j*DD + d];
      #pragma unroll
      for (int kk = 0; kk < 8; kk++) acc[kk] += wsm[(size_t)(k0 + kk)*DD + j] * wv;
    }
    #pragma unroll
    for (int kk = 0; kk < 8; kk++) WfT[(size_t)d*DSS + k0 + kk] = __float2bfloat16(acc[kk]);
  } else if (blk < 160) {
    int b2 = blk - 128, d0 = b2*8, j = tid;
    float acc[8] = {}; float accb[8] = {};
    for (int k = 0; k < DD; k++) {
      float iwv = mha_iw[(size_t)(512 + k)*DD + j];     // coalesced over j=tid
      float ibv = mha_ib[512 + k];
      #pragma unroll
      for (int dd = 0; dd < 8; dd++) {
        float owv = mha_ow[(size_t)(d0 + dd)*DD + k];    // wave broadcast
        acc[dd]  += iwv * owv;
        accb[dd] += ibv * owv;
      }
    }
    #pragma unroll
    for (int dd = 0; dd < 8; dd++) Wcv[(size_t)j*DD + d0 + dd] = acc[dd];
    if (j == 0) {
      #pragma unroll
      for (int dd = 0; dd < 8; dd++) bcv[d0 + dd] = accb[dd] + mha_ob[d0 + dd];
    }
  } else if (blk < 416) {
    int lo = blk - 160;      // 256 blocks: h = lo>>6, tile = lo&63 (8x8 of 32x32)
    dev_transpose_head(tpose, g1_lin, g1R, lo >> 6, lo & 7, (lo & 63) >> 3, tid);
  } else if (blk < 672) {
    int lo = blk - 416;
    dev_transpose_head(tpose, g2_lin, g2R, lo >> 6, lo & 7, (lo & 63) >> 3, tid);
  } else if (blk < 736) {
    int lo = blk - 672; dev_transpose(tpose, cw1, W2T, DD, DD, lo & 7, lo >> 3, tid);
  } else if (blk < 800) {
    int lo = blk - 736; dev_transpose(tpose, aw1, W2T + 65536, DD, DD, lo & 7, lo >> 3, tid);
  } else if (blk < 928) {
    int idx = (blk - 800)*256 + tid;     // 0..32767
    int n = idx >> 9, k = idx & 511;
    float v = 0.f;
    if (n < 3) { if (k < 256) v = cw2[(size_t)k*3 + n]; }
    else if (n < 23) { if (k >= 256) v = aw2[(size_t)(k - 256)*20 + (n - 3)]; }
    WdT[idx] = __float2bfloat16(v);
    if (idx < 64) bias23[idx] = idx < 3 ? cb2[idx] : (idx < 23 ? ab2[idx - 3] : 0.f);
  } else {
    int i = (blk - 928)*256 + tid;       // 0..8191
    counts[i] = 1;                       // self-loop occupies slot 0
    csr[(size_t)i*DEGC] = i;
    float4 z = make_float4(0.f, 0.f, 0.f, 0.f);
    #pragma unroll
    for (int j = 0; j < 4; j++) ((float4*)zz)[i*4 + j] = z;
    s0b[i] = 0.f; s1b[i] = 0.f;
    if (i < 256) bias2[i] = cb1[i];
    else if (i < 512) bias2[i] = ab1[i - 256];
  }
}

// ---------------------------------------------------------------------------
// prep2: mhavec + cvec + u-vectors (u = gR^T-blocks @ att) + padded-CSR fill
//  [0,32) mhavec; [32,64) cvec; [64,80) u vectors; [80,592) edge fill
// ---------------------------------------------------------------------------
__global__ __launch_bounds__(256) void prep2(
    const float* __restrict__ textf, const float* __restrict__ editp,
    const float* __restrict__ Wcv, const float* __restrict__ bcv, float* __restrict__ mhavec,
    const float* __restrict__ bs, const float* __restrict__ wp, const float* __restrict__ bp,
    float* __restrict__ cvec,
    const bf16* __restrict__ g1R, const bf16* __restrict__ g2R,
    const float* __restrict__ g1_as, const float* __restrict__ g1_ad,
    const float* __restrict__ g2_as, const float* __restrict__ g2_ad,
    float* __restrict__ u1s, float* __restrict__ u1d,
    float* __restrict__ u2s, float* __restrict__ u2d,
    const int* __restrict__ ei, int* __restrict__ counts, int* __restrict__ csr)
{
  __shared__ float red[4][64];
  int blk = blockIdx.x, tid = threadIdx.x;
  if (blk < 32) {
    int b = blk & 7, l = tid & 63, qq = tid >> 6;
    int d = (blk >> 3)*64 + l;
    float mv = 0.f;
    for (int k = qq*64; k < qq*64 + 64; k++) mv += textf[b*DD + k] * Wcv[(size_t)k*DD + d];
    red[qq][l] = mv;
    __syncthreads();
    if (tid < 64) {
      int dd = (blk >> 3)*64 + tid;
      mhavec[b*DD + dd] = red[0][tid]+red[1][tid]+red[2][tid]+red[3][tid] + bcv[dd];
    }
  } else if (blk < 64) {
    int lo = blk - 32;
    int b = lo & 7, l = tid & 63, qq = tid >> 6;
    int d = (lo >> 3)*64 + l;
    float cv = 0.f;
    for (int k = qq*64; k < qq*64 + 64; k++) cv += bs[k] * wp[(size_t)k*DD + d];
    for (int k = qq*64; k < qq*64 + 64; k++) cv += textf[b*DD + k] * wp[(size_t)(DD + k)*DD + d];
    for (int k = qq*64; k < qq*64 + 64; k++) cv += editp[b*DD + k] * wp[(size_t)(2*DD + k)*DD + d];
    red[qq][l] = cv;
    __syncthreads();
    if (tid < 64) {
      int dd = (lo >> 3)*64 + tid;
      cvec[b*DD + dd] = red[0][tid]+red[1][tid]+red[2][tid]+red[3][tid] + bp[dd] + editp[b*DD + dd];
    }
  } else if (blk < 80) {
    int lo = blk - 64;                  // 0..15
    int layer = lo >> 3, rem = lo & 7;
    int h = rem >> 1, sd = rem & 1;
    const bf16* gR = layer ? g2R : g1R;
    const float* av = layer ? (sd ? g2_ad : g2_as) : (sd ? g1_ad : g1_as);
    float* uo = layer ? (sd ? u2d : u2s) : (sd ? u1d : u1s);
    int d = tid;
    float acc = 0.f;
    for (int C = 0; C < DD; C++)
      acc += toF(gR[(size_t)C*HD + h*DD + d]) * av[h*DD + C];
    uo[h*DD + d] = acc;
  } else {
    int e = (blk - 80)*256 + tid;        // exactly NE threads
    int dn = ei[NE + e];
    int slot = atomicAdd(&counts[dn], 1);
    if (slot < DEGC) csr[(size_t)dn*DEGC + slot] = ei[e];
  }
}

// ---------------------------------------------------------------------------
// x0 GEMM, fp32 A, 64x32 tile (8 col-blocks): 1024 blocks = 4 blocks/CU =
// 16 waves/CU, doubling latency-hiding TLP (G1). fp32->bf16 in staging;
// register prefetch; fused layer-1 attention-score partials.
// ---------------------------------------------------------------------------
__global__ __launch_bounds__(256) void gemm_x0f(
    const float* __restrict__ A, const bf16* __restrict__ Bt, bf16* __restrict__ C,
    const float* __restrict__ rowvec,
    const float* __restrict__ uS, const float* __restrict__ uD,
    float* __restrict__ as_out, float* __restrict__ ad_out)
{
  __shared__ __align__(16) bf16 Asl[64*64];
  __shared__ __align__(16) bf16 Bsl[32*64];
  const int K = DSS, N = DD;
  int tid = threadIdx.x;
  int w = tid >> 6, lane = tid & 63;
  int q = lane >> 4, mn = lane & 15;
  int row0 = blockIdx.y*64, col0 = blockIdx.x*32;
  int sr = tid >> 3, sc = tid & 7;
  int swc = (sc ^ (sr & 7))*8;
  floatx4 acc[2];
  #pragma unroll
  for (int t = 0; t < 2; t++) acc[t] = (floatx4){0.f, 0.f, 0.f, 0.f};

  const float* a0p = A + (size_t)(row0 + sr)*K + sc*8;
  const float* a1p = A + (size_t)(row0 + 32 + sr)*K + sc*8;
  const bf16*  b0p = Bt + (size_t)(col0 + sr)*K + sc*8;   // sr in [0,32): 32 B-rows
  float4 f00 = *(const float4*)(a0p),     f01 = *(const float4*)(a0p + 4);
  float4 f10 = *(const float4*)(a1p),     f11 = *(const float4*)(a1p + 4);
  uint4 rb0 = *(const uint4*)(b0p);

  for (int k0 = 0; k0 < K; k0 += 64) {
    __syncthreads();
    *(uint4*)&Asl[sr*64 + swc]        = pk8(f00, f01);
    *(uint4*)&Asl[(sr + 32)*64 + swc] = pk8(f10, f11);
    *(uint4*)&Bsl[sr*64 + swc]        = rb0;
    __syncthreads();
    int kn = k0 + 64;
    if (kn < K) {                        // prefetch next tile during MFMA
      f00 = *(const float4*)(a0p + kn);  f01 = *(const float4*)(a0p + kn + 4);
      f10 = *(const float4*)(a1p + kn);  f11 = *(const float4*)(a1p + kn + 4);
      rb0 = *(const uint4*)(b0p + kn);
    }
    #pragma unroll
    for (int kk = 0; kk < 64; kk += 32) {
      int colk = (kk + q*8) ^ ((mn & 7) << 3);
      short8 af = *(const short8*)&Asl[(w*16 + mn)*64 + colk];
      #pragma unroll
      for (int t = 0; t < 2; t++) {
        short8 bfr = *(const short8*)&Bsl[(t*16 + mn)*64 + colk];
        acc[t] = __builtin_amdgcn_mfma_f32_16x16x32_bf16(af, bfr, acc[t], 0, 0, 0);
      }
    }
  }
  float vv[2][4];
  #pragma unroll
  for (int t = 0; t < 2; t++) {
    int c = col0 + t*16 + mn;
    #pragma unroll
    for (int rg = 0; rg < 4; rg++) {
      int r = row0 + w*16 + q*4 + rg;
      vv[t][rg] = acc[t][rg] + rowvec[(size_t)(r >> 10)*N + c];
    }
  }
  #pragma unroll
  for (int h = 0; h < 4; h++) {   // fused layer-1 score partials (32 cols)
    float ps[4] = {}, pd[4] = {};
    #pragma unroll
    for (int t = 0; t < 2; t++) {
      int c = col0 + t*16 + mn;
      float av = uS[h*DD + c], dv = uD[h*DD + c];
      #pragma unroll
      for (int rg = 0; rg < 4; rg++) { ps[rg] += vv[t][rg]*av; pd[rg] += vv[t][rg]*dv; }
    }
    #pragma unroll
    for (int rg = 0; rg < 4; rg++) {
      #pragma unroll
      for (int off = 1; off < 16; off <<= 1) {
        ps[rg] += __shfl_xor(ps[rg], off);
        pd[rg] += __shfl_xor(pd[rg], off);
      }
      if (mn == 0) {
        int r = row0 + w*16 + q*4 + rg;
        atomicAdd(&as_out[r*4 + h], ps[rg]);
        atomicAdd(&ad_out[r*4 + h], pd[rg]);
      }
    }
  }
  #pragma unroll
  for (int t = 0; t < 2; t++) {
    int c = col0 + t*16 + mn;
    #pragma unroll
    for (int rg = 0; rg < 4; rg++) {
      int r = row0 + w*16 + q*4 + rg;
      C[(size_t)r*N + c] = __float2bfloat16(vv[t][rg]);
    }
  }
}

// ---------------------------------------------------------------------------
// MFMA GEMM, 64x32 tile (8 col-blocks -> 1024 blocks, 4/CU, 16 waves/CU).
// Register prefetch; epilogue v = acc; +bias; relu; +rowvec. Fusions:
//  - uS/uD: per-head score partial dots -> atomicAdd as_out/ad_out
//  - ctx/ced: per-row 2-token dot partials -> atomicAdd s0b/s1b
// ---------------------------------------------------------------------------
template<typename TC>
__global__ __launch_bounds__(256) void gemm_mfma(
    const bf16* __restrict__ A, const bf16* __restrict__ Bt, TC* __restrict__ C,
    int M, int N, int K,
    const float* __restrict__ bias, int relu, const float* __restrict__ rowvec,
    const float* __restrict__ uS, const float* __restrict__ uD,
    float* __restrict__ as_out, float* __restrict__ ad_out,
    const float* __restrict__ ctx, const float* __restrict__ ced,
    float* __restrict__ s0b, float* __restrict__ s1b)
{
  __shared__ __align__(16) bf16 Asl[64*64];
  __shared__ __align__(16) bf16 Bsl[32*64];
  int tid = threadIdx.x;
  int w = tid >> 6, lane = tid & 63;
  int q = lane >> 4, mn = lane & 15;
  int row0 = blockIdx.y*64, col0 = blockIdx.x*32;
  int sr = tid >> 3, sc = tid & 7;
  int swc = (sc ^ (sr & 7))*8;           // swizzled store chunk
  floatx4 acc[2];
  #pragma unroll
  for (int t = 0; t < 2; t++) acc[t] = (floatx4){0.f, 0.f, 0.f, 0.f};

  const bf16* Ar0 = A  + (size_t)(row0 + sr)*K      + sc*8;
  const bf16* Ar1 = A  + (size_t)(row0 + 32 + sr)*K + sc*8;
  const bf16* Br0 = Bt + (size_t)(col0 + sr)*K      + sc*8;   // 32 B-rows
  uint4 ra0 = *(const uint4*)(Ar0);
  uint4 ra1 = *(const uint4*)(Ar1);
  uint4 rb0 = *(const uint4*)(Br0);

  for (int k0 = 0; k0 < K; k0 += 64) {
    __syncthreads();                     // prev MFMA done reading LDS
    *(uint4*)&Asl[sr*64 + swc]        = ra0;
    *(uint4*)&Asl[(sr + 32)*64 + swc] = ra1;
    *(uint4*)&Bsl[sr*64 + swc]        = rb0;
    __syncthreads();
    int kn = k0 + 64;
    if (kn < K) {                        // prefetch next tile during MFMA
      ra0 = *(const uint4*)(Ar0 + kn);
      ra1 = *(const uint4*)(Ar1 + kn);
      rb0 = *(const uint4*)(Br0 + kn);
    }
    #pragma unroll
    for (int kk = 0; kk < 64; kk += 32) {
      int colk = (kk + q*8) ^ ((mn & 7) << 3);
      short8 af = *(const short8*)&Asl[(w*16 + mn)*64 + colk];
      #pragma unroll
      for (int t = 0; t < 2; t++) {
        short8 bfr = *(const short8*)&Bsl[(t*16 + mn)*64 + colk];
        acc[t] = __builtin_amdgcn_mfma_f32_16x16x32_bf16(af, bfr, acc[t], 0, 0, 0);
      }
    }
  }

  // final values
  float vv[2][4];
  #pragma unroll
  for (int t = 0; t < 2; t++) {
    int c = col0 + t*16 + mn;
    #pragma unroll
    for (int rg = 0; rg < 4; rg++) {
      int r = row0 + w*16 + q*4 + rg;
      float v = acc[t][rg];
      if (bias)   v += bias[c];
      if (relu)   v = fmaxf(v, 0.f);
      if (rowvec) v += rowvec[(size_t)(r >> 10)*DD + c];
      vv[t][rg] = v;
    }
  }

  if (as_out) {  // 4-head score partials over this block's 32 cols
    #pragma unroll
    for (int h = 0; h < 4; h++) {
      float ps[4] = {}, pd[4] = {};
      #pragma unroll
      for (int t = 0; t < 2; t++) {
        int c = col0 + t*16 + mn;
        float av = uS[h*DD + c], dv = uD[h*DD + c];
        #pragma unroll
        for (int rg = 0; rg < 4; rg++) { ps[rg] += vv[t][rg]*av; pd[rg] += vv[t][rg]*dv; }
      }
      #pragma unroll
      for (int rg = 0; rg < 4; rg++) {
        #pragma unroll
        for (int off = 1; off < 16; off <<= 1) {
          ps[rg] += __shfl_xor(ps[rg], off);
          pd[rg] += __shfl_xor(pd[rg], off);
        }
        if (mn == 0) {
          int r = row0 + w*16 + q*4 + rg;
          atomicAdd(&as_out[r*4 + h], ps[rg]);
          atomicAdd(&ad_out[r*4 + h], pd[rg]);
        }
      }
    }
  }

  if (s0b) {  // per-row 2-token dot partials (batch-indexed vectors)
    int b = row0 >> 10;
    float txv[2], exv[2];
    #pragma unroll
    for (int t = 0; t < 2; t++) {
      int c = col0 + t*16 + mn;
      txv[t] = ctx[b*DD + c]; exv[t] = ced[b*DD + c];
    }
    float ss0[4] = {}, ss1[4] = {};
    #pragma unroll
    for (int t = 0; t < 2; t++)
      #pragma unroll
      for (int rg = 0; rg < 4; rg++) { ss0[rg] += vv[t][rg]*txv[t]; ss1[rg] += vv[t][rg]*exv[t]; }
    #pragma unroll
    for (int rg = 0; rg < 4; rg++) {
      #pragma unroll
      for (int off = 1; off < 16; off <<= 1) {
        ss0[rg] += __shfl_xor(ss0[rg], off);
        ss1[rg] += __shfl_xor(ss1[rg], off);
      }
      if (mn == 0) {
        int r = row0 + w*16 + q*4 + rg;
        atomicAdd(&s0b[r], ss0[rg]);
        atomicAdd(&s1b[r], ss1[rg]);
      }
    }
  }

  #pragma unroll
  for (int t = 0; t < 2; t++) {
    int c = col0 + t*16 + mn;
    #pragma unroll
    for (int rg = 0; rg < 4; rg++) {
      int r = row0 + w*16 + q*4 + rg;
      stC(&C[(size_t)r*N + c], vv[t][rg]);
    }
  }
}

// ---------------------------------------------------------------------------
// GAT gather in x-space: agg[i][h*256+d] = (0.25/den_h) * sum_j w^h_ij x[j][d].
// ---------------------------------------------------------------------------
__global__ __launch_bounds__(256) void gat_gather(
    const bf16* __restrict__ x, const float* __restrict__ a_s, const float* __restrict__ a_d,
    const int* __restrict__ cnt, const int* __restrict__ csr,
    bf16* __restrict__ agg)
{
  int i = blockIdx.x, t = threadIdx.x;
  int h = t >> 6, l = t & 63;
  int beg = i*DEGC;
  int deg = cnt[i]; if (deg > DEGC) deg = DEGC;
  __shared__ float sal[4][DEGC];
  __shared__ int   scsr[DEGC];
  float adh = a_d[i*4 + h];
  float mloc = -1e30f;
  for (int idx = l; idx < deg; idx += 64) {
    int sn = csr[beg + idx];
    if (h == 0) scsr[idx] = sn;
    float al = a_s[sn*4 + h] + adh;
    al = al > 0.f ? al : 0.2f*al;
    sal[h][idx] = al;
    mloc = fmaxf(mloc, al);
  }
  float mh = wredmax(mloc);                     // finite: deg >= 1 (self-loop)
  float sloc = 0.f;
  for (int idx = l; idx < deg; idx += 64) {
    float wv = expf(sal[h][idx] - mh);
    sal[h][idx] = wv;
    sloc += wv;
  }
  float inv = 0.25f / wredsum(sloc);            // fold head-mean 1/4 here
  __syncthreads();
  const bf16* xb = x + l*4;
  float a0 = 0.f, a1 = 0.f, a2 = 0.f, a3 = 0.f;
  for (int idx = 0; idx < deg; idx++) {
    int sn = scsr[idx];
    float wv = sal[h][idx];
    uint2 u = *(const uint2*)(xb + (size_t)sn*DD);
    a0 += wv*bf_lo(u.x); a1 += wv*bf_hi(u.x);
    a2 += wv*bf_lo(u.y); a3 += wv*bf_hi(u.y);
  }
  bf16 o[4] = {__float2bfloat16(a0*inv), __float2bfloat16(a1*inv),
               __float2bfloat16(a2*inv), __float2bfloat16(a3*inv)};
  *(uint2*)(agg + (size_t)i*HD + h*DD + l*4) = *(uint2*)o;
}

// ---------------------------------------------------------------------------
// W2 GEMM with comb applied during A-staging (unchanged, already 1024 blocks):
//   comb[r][c] = x2[r][c] + p0(r)*textf[b][c] + p1(r)*editp[b][c] + mhavec[b][c]
// where p = softmax2(s0[r], s1[r]).  h1 = relu(comb @ W2T^T + bias2) -> bf16.
// ---------------------------------------------------------------------------
__global__ __launch_bounds__(256) void gemm_w2(
    const bf16* __restrict__ A,
    const float* __restrict__ s0b, const float* __restrict__ s1b,
    const float* __restrict__ ctx, const float* __restrict__ ced,
    const float* __restrict__ cmh,
    const bf16* __restrict__ Bt, const float* __restrict__ bias,
    bf16* __restrict__ Cout)
{
  __shared__ __align__(16) bf16 Asl[64*64];
  __shared__ __align__(16) bf16 Bsl[64*64];
  const int N = 512, K = DD;
  int tid = threadIdx.x;
  int w = tid >> 6, lane = tid & 63;
  int q = lane >> 4, mn = lane & 15;
  int row0 = blockIdx.y*64, col0 = blockIdx.x*64;
  int sr = tid >> 3, sc = tid & 7;
  int swc = (sc ^ (sr & 7))*8;
  int b = row0 >> 10;
  int r0a = row0 + sr, r1a = row0 + 32 + sr;
  float p0a, p1a, p0c, p1c;
  {
    float s0 = s0b[r0a], s1 = s1b[r0a];
    float mm = fmaxf(s0, s1);
    float e0 = expf(s0 - mm), e1 = expf(s1 - mm);
    float iv = 1.f/(e0 + e1);
    p0a = e0*iv; p1a = e1*iv;
  }
  {
    float s0 = s0b[r1a], s1 = s1b[r1a];
    float mm = fmaxf(s0, s1);
    float e0 = expf(s0 - mm), e1 = expf(s1 - mm);
    float iv = 1.f/(e0 + e1);
    p0c = e0*iv; p1c = e1*iv;
  }
  floatx4 acc[4];
  #pragma unroll
  for (int t = 0; t < 4; t++) acc[t] = (floatx4){0.f, 0.f, 0.f, 0.f};

  for (int k0 = 0; k0 < K; k0 += 64) {
    int kc = k0 + sc*8;
    float4 t0 = *(const float4*)(ctx + b*DD + kc);
    float4 t1 = *(const float4*)(ctx + b*DD + kc + 4);
    float4 e0v = *(const float4*)(ced + b*DD + kc);
    float4 e1v = *(const float4*)(ced + b*DD + kc + 4);
    float4 m0 = *(const float4*)(cmh + b*DD + kc);
    float4 m1 = *(const float4*)(cmh + b*DD + kc + 4);
    uint4 ua = *(const uint4*)(A + (size_t)r0a*DD + kc);
    uint4 ub = *(const uint4*)(A + (size_t)r1a*DD + kc);
    float4 fa0 = make_float4(bf_lo(ua.x), bf_hi(ua.x), bf_lo(ua.y), bf_hi(ua.y));
    float4 fa1 = make_float4(bf_lo(ua.z), bf_hi(ua.z), bf_lo(ua.w), bf_hi(ua.w));
    float4 fb0 = make_float4(bf_lo(ub.x), bf_hi(ub.x), bf_lo(ub.y), bf_hi(ub.y));
    float4 fb1 = make_float4(bf_lo(ub.z), bf_hi(ub.z), bf_lo(ub.w), bf_hi(ub.w));
    fa0 = combf(fa0, t0, e0v, m0, p0a, p1a);
    fa1 = combf(fa1, t1, e1v, m1, p0a, p1a);
    fb0 = combf(fb0, t0, e0v, m0, p0c, p1c);
    fb1 = combf(fb1, t1, e1v, m1, p0c, p1c);
    uint4 b0 = *(const uint4*)(Bt + (size_t)(col0 + sr)*K      + k0 + sc*8);
    uint4 b1 = *(const uint4*)(Bt + (size_t)(col0 + 32 + sr)*K + k0 + sc*8);
    __syncthreads();
    *(uint4*)&Asl[sr*64 + swc]        = pk8(fa0, fa1);
    *(uint4*)&Asl[(sr + 32)*64 + swc] = pk8(fb0, fb1);
    *(uint4*)&Bsl[sr*64 + swc]        = b0;
    *(uint4*)&Bsl[(sr + 32)*64 + swc] = b1;
    __syncthreads();
    #pragma unroll
    for (int kk = 0; kk < 64; kk += 32) {
      int colk = (kk + q*8) ^ ((mn & 7) << 3);
      short8 af = *(const short8*)&Asl[(w*16 + mn)*64 + colk];
      #pragma unroll
      for (int t = 0; t < 4; t++) {
        short8 bfr = *(const short8*)&Bsl[(t*16 + mn)*64 + colk];
        acc[t] = __builtin_amdgcn_mfma_f32_16x16x32_bf16(af, bfr, acc[t], 0, 0, 0);
      }
    }
  }
  #pragma unroll
  for (int t = 0; t < 4; t++) {
    #pragma unroll
    for (int rg = 0; rg < 4; rg++) {
      int r = row0 + w*16 + q*4 + rg;
      int c = col0 + t*16 + mn;
      float v = fmaxf(acc[t][rg] + bias[c], 0.f);
      Cout[(size_t)r*N + c] = __float2bfloat16(v);
    }
  }
}

// ---------------------------------------------------------------------------
// final-head GEMM (K=512, N=64, block-diag Wd) + fused per-row softmax.
// ---------------------------------------------------------------------------
__global__ __launch_bounds__(256) void gemm_fin(
    const bf16* __restrict__ A, const bf16* __restrict__ Bt,
    const float* __restrict__ bias, float* __restrict__ out)
{
  __shared__ __align__(16) bf16 Asl[64*64];
  __shared__ __align__(16) bf16 Bsl[64*64];
  const int K = 512;
  int tid = threadIdx.x;
  int w = tid >> 6, lane = tid & 63;
  int q = lane >> 4, mn = lane & 15;
  int row0 = blockIdx.x*64;
  int sr = tid >> 3, sc = tid & 7;
  int swc = (sc ^ (sr & 7))*8;
  floatx4 acc[4];
  #pragma unroll
  for (int t = 0; t < 4; t++) acc[t] = (floatx4){0.f, 0.f, 0.f, 0.f};
  for (int k0 = 0; k0 < K; k0 += 64) {
    uint4 a0 = *(const uint4*)(A  + (size_t)(row0 + sr)*K      + k0 + sc*8);
    uint4 a1 = *(const uint4*)(A  + (size_t)(row0 + 32 + sr)*K + k0 + sc*8);
    uint4 b0 = *(const uint4*)(Bt + (size_t)sr*K      + k0 + sc*8);
    uint4 b1 = *(const uint4*)(Bt + (size_t)(32 + sr)*K + k0 + sc*8);
    __syncthreads();
    *(uint4*)&Asl[sr*64 + swc]        = a0;
    *(uint4*)&Asl[(sr + 32)*64 + swc] = a1;
    *(uint4*)&Bsl[sr*64 + swc]        = b0;
    *(uint4*)&Bsl[(sr + 32)*64 + swc] = b1;
    __syncthreads();
    #pragma unroll
    for (int kk = 0; kk < 64; kk += 32) {
      int colk = (kk + q*8) ^ ((mn & 7) << 3);
      short8 af = *(const short8*)&Asl[(w*16 + mn)*64 + colk];
      #pragma unroll
      for (int t = 0; t < 4; t++) {
        short8 bfr = *(const short8*)&Bsl[(t*16 + mn)*64 + colk];
        acc[t] = __builtin_amdgcn_mfma_f32_16x16x32_bf16(af, bfr, acc[t], 0, 0, 0);
      }
    }
  }
  #pragma unroll
  for (int rg = 0; rg < 4; rg++) {
    int r = row0 + w*16 + q*4 + rg;
    float mx = -1e30f;
    #pragma unroll
    for (int t = 0; t < 4; t++) {
      int c = t*16 + mn;
      float val = acc[t][rg] + bias[c];
      if (c >= 3 && c < 23) mx = fmaxf(mx, val);
    }
    #pragma unroll
    for (int off = 1; off < 16; off <<= 1) mx = fmaxf(mx, __shfl_xor(mx, off));
    float sum = 0.f;
    #pragma unroll
    for (int t = 0; t < 4; t++) {
      int c = t*16 + mn;
      float val = acc[t][rg] + bias[c];
      if (c >= 3 && c < 23) sum += expf(val - mx);
    }
    #pragma unroll
    for (int off = 1; off < 16; off <<= 1) sum += __shfl_xor(sum, off);
    float inv = 1.f / sum;
    #pragma unroll
    for (int t = 0; t < 2; t++) {
      int c = t*16 + mn;
      float val = acc[t][rg] + bias[c];
      if (c < 3) out[(size_t)r*3 + c] = val;
      else if (c < 23) out[24576 + (size_t)r*20 + (c - 3)] = expf(val - mx)*inv;
    }
  }
}

// ---------------------------------------------------------------------------
extern "C" void kernel_launch(void* const* d_in, const int* in_sizes, int n_in,
                              void* d_out, int out_size, void* d_ws, size_t ws_size,
                              hipStream_t stream)
{
  (void)in_sizes; (void)n_in; (void)out_size; (void)ws_size;
  const float* structure_emb = (const float*)d_in[0];
  const float* text_emb      = (const float*)d_in[1];
  const float* edit_emb      = (const float*)d_in[3];
  const float* ws_w    = (const float*)d_in[4];
  const float* bs_b    = (const float*)d_in[5];
  const float* wt_w    = (const float*)d_in[6];
  const float* bt_b    = (const float*)d_in[7];
  const float* we_w    = (const float*)d_in[8];
  const float* be_b    = (const float*)d_in[9];
  const float* wp_w    = (const float*)d_in[10];
  const float* bp_b    = (const float*)d_in[11];
  const float* g1_lin  = (const float*)d_in[12];
  const float* g1_as   = (const float*)d_in[13];
  const float* g1_ad   = (const float*)d_in[14];
  const float* g1_b    = (const float*)d_in[15];
  const float* g2_lin  = (const float*)d_in[16];
  const float* g2_as   = (const float*)d_in[17];
  const float* g2_ad   = (const float*)d_in[18];
  const float* g2_b    = (const float*)d_in[19];
  const float* mha_iw  = (const float*)d_in[20];
  const float* mha_ib  = (const float*)d_in[21];
  const float* mha_ow  = (const float*)d_in[22];
  const float* mha_ob  = (const float*)d_in[23];
  const float* cw1     = (const float*)d_in[24];
  const float* cb1     = (const float*)d_in[25];
  const float* cw2     = (const float*)d_in[26];
  const float* cb2     = (const float*)d_in[27];
  const float* aw1     = (const float*)d_in[28];
  const float* ab1     = (const float*)d_in[29];
  const float* aw2     = (const float*)d_in[30];
  const float* ab2     = (const float*)d_in[31];
  const int*  edge_index = (const int*)d_in[32];
  float* out = (float*)d_out;

  // --- workspace layout (~27.9 MB, proven envelope) ---
  char* p = (char*)d_ws;
  // 16 MB big region, time-multiplexed: agg (16MB) -> h1b (8MB)
  bf16*  aggb  = (bf16*)p;
  bf16*  h1b   = (bf16*)p;
  p += 16777216;
  bf16* bufB = (bf16*)p; p += 4194304;   // [8192][256] bf16: x0 -> x1e -> x2
  bf16* g1R  = (bf16*)p; p += 524288;    // [256][1024] per-head transposed g1_lin
  bf16* g2R  = (bf16*)p; p += 524288;
  bf16* W2T  = (bf16*)p; p += 262144;    // [512][256]: cw1T ++ aw1T
  bf16* WfT  = (bf16*)p; p += 393216;    // [256][768]
  bf16* WdT  = (bf16*)p; p += 65536;     // [64][512] block-diag final weight
  float* Wcv = (float*)p; p += 262144;   // [256][256] fp32 collapsed MHA weight
  float* bcv = (float*)p; p += 1024;
  float* textf  = (float*)p; p += 8192;
  float* editp  = (float*)p; p += 8192;
  float* mhavec = (float*)p; p += 8192;
  float* cvec   = (float*)p; p += 8192;
  float* bias2  = (float*)p; p += 2048;
  float* bias23 = (float*)p; p += 256;
  float* u1s = (float*)p; p += 4096;     // [4][256] score vectors
  float* u1d = (float*)p; p += 4096;
  float* u2s = (float*)p; p += 4096;
  float* u2d = (float*)p; p += 4096;
  float* a_s1   = (float*)p; p += 131072;  // zz block: a_s1,a_d1,a_s2,a_d2
  float* a_d1   = (float*)p; p += 131072;
  float* a_s2   = (float*)p; p += 131072;
  float* a_d2   = (float*)p; p += 131072;
  float* s0b    = (float*)p; p += 32768;   // [8192] comb dot partials
  float* s1b    = (float*)p; p += 32768;
  int* counts = (int*)p; p += 32768;
  int* csr    = (int*)p; p += BN*DEGC*4;   // padded CSR, 4 MB

  prep1<<<960, 256, 0, stream>>>(
      text_emb, edit_emb, wt_w, bt_b, we_w, be_b, textf, editp,
      ws_w, wp_w, WfT,
      mha_iw, mha_ib, mha_ow, mha_ob, Wcv, bcv,
      g1_lin, g1R, g2_lin, g2R, cw1, aw1, W2T,
      cw2, cb2, aw2, ab2, WdT, bias23,
      counts, csr, a_s1, s0b, s1b, cb1, ab1, bias2);
  prep2<<<592, 256, 0, stream>>>(
      textf, editp, Wcv, bcv, mhavec, bs_b, wp_w, bp_b, cvec,
      g1R, g2R, g1_as, g1_ad, g2_as, g2_ad, u1s, u1d, u2s, u2d,
      edge_index, counts, csr);

  // x0 = bf16(semb) @ Wfull + cvec[batch] -> bufB; fused layer-1 scores
  gemm_x0f<<<dim3(DD/32, BN/64), 256, 0, stream>>>(
      structure_emb, WfT, bufB, cvec, u1s, u1d, a_s1, a_d1);

  // GAT layer 1: gather in x-space -> agg1; x1e = relu(agg1@g1R + b1) + edit
  gat_gather<<<BN, 256, 0, stream>>>(bufB, a_s1, a_d1, counts, csr, aggb);
  gemm_mfma<bf16><<<dim3(DD/32, BN/64), 256, 0, stream>>>(
      aggb, g1R, bufB, BN, DD, HD, g1_b, 1, editp,
      u2s, u2d, a_s2, a_d2, nullptr, nullptr, nullptr, nullptr);

  // GAT layer 2: gather -> agg2; x2 = relu(agg2@g2R + b2) -> bufB; comb dots
  gat_gather<<<BN, 256, 0, stream>>>(bufB, a_s2, a_d2, counts, csr, aggb);
  gemm_mfma<bf16><<<dim3(DD/32, BN/64), 256, 0, stream>>>(
      aggb, g2R, bufB, BN, DD, HD, g2_b, 1, nullptr,
      nullptr, nullptr, nullptr, nullptr, textf, editp, s0b, s1b);

  // W2 head: comb in staging -> h1b (aggb dead by now)
  gemm_w2<<<dim3(8, BN/64), 256, 0, stream>>>(
      bufB, s0b, s1b, textf, editp, mhavec, W2T, bias2, h1b);

  // final projection + fused softmax -> d_out
  gemm_fin<<<BN/64, 256, 0, stream>>>(h1b, WdT, bias23, out);
}

// Round 13
// 326.398 us; speedup vs baseline: 1.1791x; 1.1791x over previous
//
#include <hip/hip_runtime.h>
#include <hip/hip_bf16.h>

// Problem constants
#define BB 8
#define NN 1024
#define BN 8192       // B*N
#define DD 256
#define HEADS 4
#define HD 1024       // HEADS*D
#define DSS 768
#define DTT 128
#define NE 131072     // raw edges
#define DEGC 128      // padded CSR slots per node (max in-degree ~41 incl. self-loop)

typedef __hip_bfloat16 bf16;
typedef __attribute__((ext_vector_type(8))) short short8;   // 8 bf16 (4 VGPRs)
typedef __attribute__((ext_vector_type(4))) float floatx4;  // MFMA C/D

__device__ __forceinline__ float toF(bf16 x){ return __bfloat162float(x); }
__device__ __forceinline__ void stC(float* p, float v){ *p = v; }
__device__ __forceinline__ void stC(bf16* p, float v){ *p = __float2bfloat16(v); }
__device__ __forceinline__ float bf_lo(unsigned u){ return __uint_as_float(u << 16); }
__device__ __forceinline__ float bf_hi(unsigned u){ return __uint_as_float(u & 0xffff0000u); }

__device__ __forceinline__ uint4 pk8(float4 a, float4 b){
  bf16 t[8] = {__float2bfloat16(a.x),__float2bfloat16(a.y),__float2bfloat16(a.z),__float2bfloat16(a.w),
               __float2bfloat16(b.x),__float2bfloat16(b.y),__float2bfloat16(b.z),__float2bfloat16(b.w)};
  return *(uint4*)t;
}
__device__ __forceinline__ float4 combf(float4 a, float4 t, float4 e, float4 m, float p0, float p1){
  a.x += p0*t.x + p1*e.x + m.x;
  a.y += p0*t.y + p1*e.y + m.y;
  a.z += p0*t.z + p1*e.z + m.z;
  a.w += p0*t.w + p1*e.w + m.w;
  return a;
}

__device__ __forceinline__ float wredsum(float v){
  #pragma unroll
  for (int off = 32; off; off >>= 1) v += __shfl_xor(v, off);
  return v;
}
__device__ __forceinline__ float wredmax(float v){
  #pragma unroll
  for (int off = 32; off; off >>= 1) v = fmaxf(v, __shfl_xor(v, off));
  return v;
}

// transpose one 32x32 tile: dst[c][r] = bf16(src[r][c]) (whole block same branch)
__device__ __forceinline__ void dev_transpose(
    float tb[32][33], const float* __restrict__ src, bf16* __restrict__ dst,
    int R, int C, int bx, int by, int tid)
{
  int c0 = bx*32, r0 = by*32;
  int tr = tid >> 5, tc = tid & 31;
  #pragma unroll
  for (int i = 0; i < 4; i++)
    tb[tr + i*8][tc] = src[(size_t)(r0 + tr + i*8)*C + c0 + tc];
  __syncthreads();
  #pragma unroll
  for (int i = 0; i < 4; i++)
    dst[(size_t)(c0 + tr + i*8)*R + r0 + tc] = __float2bfloat16(tb[tc][tr + i*8]);
}

// per-head transpose: dst[c][h*256+d] = src[d][h*256+c]  (src,dst both stride HD)
__device__ __forceinline__ void dev_transpose_head(
    float tb[32][33], const float* __restrict__ src, bf16* __restrict__ dst,
    int h, int bx, int by, int tid)
{
  int c0 = bx*32, r0 = by*32;
  int tr = tid >> 5, tc = tid & 31;
  #pragma unroll
  for (int i = 0; i < 4; i++)
    tb[tr + i*8][tc] = src[(size_t)(r0 + tr + i*8)*HD + h*DD + c0 + tc];
  __syncthreads();
  #pragma unroll
  for (int i = 0; i < 4; i++)
    dst[(size_t)(c0 + tr + i*8)*HD + h*DD + r0 + tc] = __float2bfloat16(tb[tc][tr + i*8]);
}

// ---------------------------------------------------------------------------
// prep1: ALL independent prep work in one launch, partitioned by block range.
//  [0,32)    textf/editp projections
//  [32,128)  WfullT (ws@wp fused weight, transposed bf16)
//  [128,160) Wcv = iw_v^T @ ow^T (+ bcv)
//  [160,416) g1_lin per-head transpose -> g1R
//  [416,672) g2_lin per-head transpose -> g2R
//  [672,736) cw1 transpose -> W2T[0:256]
//  [736,800) aw1 transpose -> W2T[256:512]
//  [800,928) WdT block-diag final weight + bias23
//  [928,960) padded-CSR init + zero a_s/a_d + s0b/s1b + bias2
// ---------------------------------------------------------------------------
__global__ __launch_bounds__(256) void prep1(
    const float* __restrict__ text_emb, const float* __restrict__ edit_emb,
    const float* __restrict__ wt, const float* __restrict__ bt,
    const float* __restrict__ we, const float* __restrict__ be,
    float* __restrict__ textf, float* __restrict__ editp,
    const float* __restrict__ wsm, const float* __restrict__ wp, bf16* __restrict__ WfT,
    const float* __restrict__ mha_iw, const float* __restrict__ mha_ib,
    const float* __restrict__ mha_ow, const float* __restrict__ mha_ob,
    float* __restrict__ Wcv, float* __restrict__ bcv,
    const float* __restrict__ g1_lin, bf16* __restrict__ g1R,
    const float* __restrict__ g2_lin, bf16* __restrict__ g2R,
    const float* __restrict__ cw1, const float* __restrict__ aw1, bf16* __restrict__ W2T,
    const float* __restrict__ cw2, const float* __restrict__ cb2,
    const float* __restrict__ aw2, const float* __restrict__ ab2,
    bf16* __restrict__ WdT, float* __restrict__ bias23,
    int* __restrict__ counts, int* __restrict__ csr, float* __restrict__ zz,
    float* __restrict__ s0b, float* __restrict__ s1b,
    const float* __restrict__ cb1, const float* __restrict__ ab1, float* __restrict__ bias2)
{
  __shared__ float tpose[32][33];
  __shared__ float red[2][4][64];
  int blk = blockIdx.x, tid = threadIdx.x;
  if (blk < 32) {
    int b = blk & 7, l = tid & 63, qq = tid >> 6;
    int d = (blk >> 3)*64 + l;
    float tf = 0.f;
    for (int k = qq*32; k < qq*32 + 32; k++) tf += text_emb[b*DTT + k] * wt[(size_t)k*DD + d];
    float ep = 0.f;
    for (int k = qq*192; k < qq*192 + 192; k++) ep += edit_emb[b*DSS + k] * we[(size_t)k*DD + d];
    red[0][qq][l] = tf; red[1][qq][l] = ep;
    __syncthreads();
    if (tid < 64) {
      int dd = (blk >> 3)*64 + tid;
      textf[b*DD + dd] = red[0][0][tid]+red[0][1][tid]+red[0][2][tid]+red[0][3][tid] + bt[dd];
      editp[b*DD + dd] = red[1][0][tid]+red[1][1][tid]+red[1][2][tid]+red[1][3][tid] + be[dd];
    }
  } else if (blk < 128) {
    int k0 = (blk - 32)*8, d = tid;
    float acc[8] = {};
    for (int j = 0; j < DD; j++) {
      float wv = wp[(size_t)j*DD + d];
      #pragma unroll
      for (int kk = 0; kk < 8; kk++) acc[kk] += wsm[(size_t)(k0 + kk)*DD + j] * wv;
    }
    #pragma unroll
    for (int kk = 0; kk < 8; kk++) WfT[(size_t)d*DSS + k0 + kk] = __float2bfloat16(acc[kk]);
  } else if (blk < 160) {
    int b2 = blk - 128, d0 = b2*8, j = tid;
    float acc[8] = {}; float accb[8] = {};
    for (int k = 0; k < DD; k++) {
      float iwv = mha_iw[(size_t)(512 + k)*DD + j];     // coalesced over j=tid
      float ibv = mha_ib[512 + k];
      #pragma unroll
      for (int dd = 0; dd < 8; dd++) {
        float owv = mha_ow[(size_t)(d0 + dd)*DD + k];    // wave broadcast
        acc[dd]  += iwv * owv;
        accb[dd] += ibv * owv;
      }
    }
    #pragma unroll
    for (int dd = 0; dd < 8; dd++) Wcv[(size_t)j*DD + d0 + dd] = acc[dd];
    if (j == 0) {
      #pragma unroll
      for (int dd = 0; dd < 8; dd++) bcv[d0 + dd] = accb[dd] + mha_ob[d0 + dd];
    }
  } else if (blk < 416) {
    int lo = blk - 160;      // 256 blocks: h = lo>>6, tile = lo&63 (8x8 of 32x32)
    dev_transpose_head(tpose, g1_lin, g1R, lo >> 6, lo & 7, (lo & 63) >> 3, tid);
  } else if (blk < 672) {
    int lo = blk - 416;
    dev_transpose_head(tpose, g2_lin, g2R, lo >> 6, lo & 7, (lo & 63) >> 3, tid);
  } else if (blk < 736) {
    int lo = blk - 672; dev_transpose(tpose, cw1, W2T, DD, DD, lo & 7, lo >> 3, tid);
  } else if (blk < 800) {
    int lo = blk - 736; dev_transpose(tpose, aw1, W2T + 65536, DD, DD, lo & 7, lo >> 3, tid);
  } else if (blk < 928) {
    int idx = (blk - 800)*256 + tid;     // 0..32767
    int n = idx >> 9, k = idx & 511;
    float v = 0.f;
    if (n < 3) { if (k < 256) v = cw2[(size_t)k*3 + n]; }
    else if (n < 23) { if (k >= 256) v = aw2[(size_t)(k - 256)*20 + (n - 3)]; }
    WdT[idx] = __float2bfloat16(v);
    if (idx < 64) bias23[idx] = idx < 3 ? cb2[idx] : (idx < 23 ? ab2[idx - 3] : 0.f);
  } else {
    int i = (blk - 928)*256 + tid;       // 0..8191
    counts[i] = 1;                       // self-loop occupies slot 0
    csr[(size_t)i*DEGC] = i;
    float4 z = make_float4(0.f, 0.f, 0.f, 0.f);
    #pragma unroll
    for (int j = 0; j < 4; j++) ((float4*)zz)[i*4 + j] = z;
    s0b[i] = 0.f; s1b[i] = 0.f;
    if (i < 256) bias2[i] = cb1[i];
    else if (i < 512) bias2[i] = ab1[i - 256];
  }
}

// ---------------------------------------------------------------------------
// prep2: mhavec + cvec + u-vectors (u = gR^T-blocks @ att) + padded-CSR fill
//  [0,32) mhavec; [32,64) cvec; [64,80) u vectors; [80,592) edge fill
// ---------------------------------------------------------------------------
__global__ __launch_bounds__(256) void prep2(
    const float* __restrict__ textf, const float* __restrict__ editp,
    const float* __restrict__ Wcv, const float* __restrict__ bcv, float* __restrict__ mhavec,
    const float* __restrict__ bs, const float* __restrict__ wp, const float* __restrict__ bp,
    float* __restrict__ cvec,
    const bf16* __restrict__ g1R, const bf16* __restrict__ g2R,
    const float* __restrict__ g1_as, const float* __restrict__ g1_ad,
    const float* __restrict__ g2_as, const float* __restrict__ g2_ad,
    float* __restrict__ u1s, float* __restrict__ u1d,
    float* __restrict__ u2s, float* __restrict__ u2d,
    const int* __restrict__ ei, int* __restrict__ counts, int* __restrict__ csr)
{
  __shared__ float red[4][64];
  int blk = blockIdx.x, tid = threadIdx.x;
  if (blk < 32) {
    int b = blk & 7, l = tid & 63, qq = tid >> 6;
    int d = (blk >> 3)*64 + l;
    float mv = 0.f;
    for (int k = qq*64; k < qq*64 + 64; k++) mv += textf[b*DD + k] * Wcv[(size_t)k*DD + d];
    red[qq][l] = mv;
    __syncthreads();
    if (tid < 64) {
      int dd = (blk >> 3)*64 + tid;
      mhavec[b*DD + dd] = red[0][tid]+red[1][tid]+red[2][tid]+red[3][tid] + bcv[dd];
    }
  } else if (blk < 64) {
    int lo = blk - 32;
    int b = lo & 7, l = tid & 63, qq = tid >> 6;
    int d = (lo >> 3)*64 + l;
    float cv = 0.f;
    for (int k = qq*64; k < qq*64 + 64; k++) cv += bs[k] * wp[(size_t)k*DD + d];
    for (int k = qq*64; k < qq*64 + 64; k++) cv += textf[b*DD + k] * wp[(size_t)(DD + k)*DD + d];
    for (int k = qq*64; k < qq*64 + 64; k++) cv += editp[b*DD + k] * wp[(size_t)(2*DD + k)*DD + d];
    red[qq][l] = cv;
    __syncthreads();
    if (tid < 64) {
      int dd = (lo >> 3)*64 + tid;
      cvec[b*DD + dd] = red[0][tid]+red[1][tid]+red[2][tid]+red[3][tid] + bp[dd] + editp[b*DD + dd];
    }
  } else if (blk < 80) {
    int lo = blk - 64;                  // 0..15
    int layer = lo >> 3, rem = lo & 7;
    int h = rem >> 1, sd = rem & 1;
    const bf16* gR = layer ? g2R : g1R;
    const float* av = layer ? (sd ? g2_ad : g2_as) : (sd ? g1_ad : g1_as);
    float* uo = layer ? (sd ? u2d : u2s) : (sd ? u1d : u1s);
    int d = tid;
    float acc = 0.f;
    for (int C = 0; C < DD; C++)
      acc += toF(gR[(size_t)C*HD + h*DD + d]) * av[h*DD + C];
    uo[h*DD + d] = acc;
  } else {
    int e = (blk - 80)*256 + tid;        // exactly NE threads
    int dn = ei[NE + e];
    int slot = atomicAdd(&counts[dn], 1);
    if (slot < DEGC) csr[(size_t)dn*DEGC + slot] = ei[e];
  }
}

// ---------------------------------------------------------------------------
// x0 GEMM, fp32 A, with register-prefetch double-buffer: loads for K-tile k+1
// issue right after the LDS stores of tile k, hiding HBM latency under the
// MFMA loop (G7). Conversion fp32->bf16 stays fused in staging.
// Fused layer-1 attention-score partials.
// 64x64 tile: measured optimum (64x32 doubled A re-reads -> HBM-bound, r12).
// ---------------------------------------------------------------------------
__global__ __launch_bounds__(256) void gemm_x0f(
    const float* __restrict__ A, const bf16* __restrict__ Bt, bf16* __restrict__ C,
    const float* __restrict__ rowvec,
    const float* __restrict__ uS, const float* __restrict__ uD,
    float* __restrict__ as_out, float* __restrict__ ad_out)
{
  __shared__ __align__(16) bf16 Asl[64*64];
  __shared__ __align__(16) bf16 Bsl[64*64];
  const int K = DSS, N = DD;
  int tid = threadIdx.x;
  int w = tid >> 6, lane = tid & 63;
  int q = lane >> 4, mn = lane & 15;
  int row0 = blockIdx.y*64, col0 = blockIdx.x*64;
  int sr = tid >> 3, sc = tid & 7;
  int swc = (sc ^ (sr & 7))*8;
  floatx4 acc[4];
  #pragma unroll
  for (int t = 0; t < 4; t++) acc[t] = (floatx4){0.f, 0.f, 0.f, 0.f};

  const float* a0p = A + (size_t)(row0 + sr)*K + sc*8;
  const float* a1p = A + (size_t)(row0 + 32 + sr)*K + sc*8;
  const bf16*  b0p = Bt + (size_t)(col0 + sr)*K + sc*8;
  const bf16*  b1p = Bt + (size_t)(col0 + 32 + sr)*K + sc*8;
  float4 f00 = *(const float4*)(a0p),     f01 = *(const float4*)(a0p + 4);
  float4 f10 = *(const float4*)(a1p),     f11 = *(const float4*)(a1p + 4);
  uint4 rb0 = *(const uint4*)(b0p);
  uint4 rb1 = *(const uint4*)(b1p);

  for (int k0 = 0; k0 < K; k0 += 64) {
    __syncthreads();
    *(uint4*)&Asl[sr*64 + swc]        = pk8(f00, f01);
    *(uint4*)&Asl[(sr + 32)*64 + swc] = pk8(f10, f11);
    *(uint4*)&Bsl[sr*64 + swc]        = rb0;
    *(uint4*)&Bsl[(sr + 32)*64 + swc] = rb1;
    __syncthreads();
    int kn = k0 + 64;
    if (kn < K) {                        // prefetch next tile during MFMA
      f00 = *(const float4*)(a0p + kn);  f01 = *(const float4*)(a0p + kn + 4);
      f10 = *(const float4*)(a1p + kn);  f11 = *(const float4*)(a1p + kn + 4);
      rb0 = *(const uint4*)(b0p + kn);
      rb1 = *(const uint4*)(b1p + kn);
    }
    #pragma unroll
    for (int kk = 0; kk < 64; kk += 32) {
      int colk = (kk + q*8) ^ ((mn & 7) << 3);
      short8 af = *(const short8*)&Asl[(w*16 + mn)*64 + colk];
      #pragma unroll
      for (int t = 0; t < 4; t++) {
        short8 bfr = *(const short8*)&Bsl[(t*16 + mn)*64 + colk];
        acc[t] = __builtin_amdgcn_mfma_f32_16x16x32_bf16(af, bfr, acc[t], 0, 0, 0);
      }
    }
  }
  float vv[4][4];
  #pragma unroll
  for (int t = 0; t < 4; t++) {
    int c = col0 + t*16 + mn;
    #pragma unroll
    for (int rg = 0; rg < 4; rg++) {
      int r = row0 + w*16 + q*4 + rg;
      vv[t][rg] = acc[t][rg] + rowvec[(size_t)(r >> 10)*N + c];
    }
  }
  #pragma unroll
  for (int h = 0; h < 4; h++) {   // fused layer-1 score partials
    float ps[4] = {}, pd[4] = {};
    #pragma unroll
    for (int t = 0; t < 4; t++) {
      int c = col0 + t*16 + mn;
      float av = uS[h*DD + c], dv = uD[h*DD + c];
      #pragma unroll
      for (int rg = 0; rg < 4; rg++) { ps[rg] += vv[t][rg]*av; pd[rg] += vv[t][rg]*dv; }
    }
    #pragma unroll
    for (int rg = 0; rg < 4; rg++) {
      #pragma unroll
      for (int off = 1; off < 16; off <<= 1) {
        ps[rg] += __shfl_xor(ps[rg], off);
        pd[rg] += __shfl_xor(pd[rg], off);
      }
      if (mn == 0) {
        int r = row0 + w*16 + q*4 + rg;
        atomicAdd(&as_out[r*4 + h], ps[rg]);
        atomicAdd(&ad_out[r*4 + h], pd[rg]);
      }
    }
  }
  #pragma unroll
  for (int t = 0; t < 4; t++) {
    int c = col0 + t*16 + mn;
    #pragma unroll
    for (int rg = 0; rg < 4; rg++) {
      int r = row0 + w*16 + q*4 + rg;
      C[(size_t)r*N + c] = __float2bfloat16(vv[t][rg]);
    }
  }
}

// ---------------------------------------------------------------------------
// MFMA GEMM: C[M,N] = A[M,K] @ Bt[N,K]^T, bf16 in, fp32 acc, 64x64 tile.
// Register-prefetch double-buffer. 64x64 is the measured tile optimum
// (64x32 raised occupancy but doubled A re-reads -> net regression, r12).
// Epilogue order: v = acc; +bias; relu; +rowvec. Optional fusions on v:
//  - uS/uD [4][256]: per-head score partial dots -> atomicAdd as_out/ad_out
//  - ctx/ced: per-row 2-token dot partials -> atomicAdd s0b/s1b
// ---------------------------------------------------------------------------
template<typename TC>
__global__ __launch_bounds__(256) void gemm_mfma(
    const bf16* __restrict__ A, const bf16* __restrict__ Bt, TC* __restrict__ C,
    int M, int N, int K,
    const float* __restrict__ bias, int relu, const float* __restrict__ rowvec,
    const float* __restrict__ uS, const float* __restrict__ uD,
    float* __restrict__ as_out, float* __restrict__ ad_out,
    const float* __restrict__ ctx, const float* __restrict__ ced,
    float* __restrict__ s0b, float* __restrict__ s1b)
{
  __shared__ __align__(16) bf16 Asl[64*64];
  __shared__ __align__(16) bf16 Bsl[64*64];
  int tid = threadIdx.x;
  int w = tid >> 6, lane = tid & 63;
  int q = lane >> 4, mn = lane & 15;
  int row0 = blockIdx.y*64, col0 = blockIdx.x*64;
  int sr = tid >> 3, sc = tid & 7;
  int swc = (sc ^ (sr & 7))*8;           // swizzled store chunk
  floatx4 acc[4];
  #pragma unroll
  for (int t = 0; t < 4; t++) acc[t] = (floatx4){0.f, 0.f, 0.f, 0.f};

  const bf16* Ar0 = A  + (size_t)(row0 + sr)*K      + sc*8;
  const bf16* Ar1 = A  + (size_t)(row0 + 32 + sr)*K + sc*8;
  const bf16* Br0 = Bt + (size_t)(col0 + sr)*K      + sc*8;
  const bf16* Br1 = Bt + (size_t)(col0 + 32 + sr)*K + sc*8;
  uint4 ra0 = *(const uint4*)(Ar0);
  uint4 ra1 = *(const uint4*)(Ar1);
  uint4 rb0 = *(const uint4*)(Br0);
  uint4 rb1 = *(const uint4*)(Br1);

  for (int k0 = 0; k0 < K; k0 += 64) {
    __syncthreads();                     // prev MFMA done reading LDS
    *(uint4*)&Asl[sr*64 + swc]        = ra0;
    *(uint4*)&Asl[(sr + 32)*64 + swc] = ra1;
    *(uint4*)&Bsl[sr*64 + swc]        = rb0;
    *(uint4*)&Bsl[(sr + 32)*64 + swc] = rb1;
    __syncthreads();
    int kn = k0 + 64;
    if (kn < K) {                        // prefetch next tile during MFMA
      ra0 = *(const uint4*)(Ar0 + kn);
      ra1 = *(const uint4*)(Ar1 + kn);
      rb0 = *(const uint4*)(Br0 + kn);
      rb1 = *(const uint4*)(Br1 + kn);
    }
    #pragma unroll
    for (int kk = 0; kk < 64; kk += 32) {
      int colk = (kk + q*8) ^ ((mn & 7) << 3);
      short8 af = *(const short8*)&Asl[(w*16 + mn)*64 + colk];
      #pragma unroll
      for (int t = 0; t < 4; t++) {
        short8 bfr = *(const short8*)&Bsl[(t*16 + mn)*64 + colk];
        acc[t] = __builtin_amdgcn_mfma_f32_16x16x32_bf16(af, bfr, acc[t], 0, 0, 0);
      }
    }
  }

  // final values
  float vv[4][4];
  #pragma unroll
  for (int t = 0; t < 4; t++) {
    int c = col0 + t*16 + mn;
    #pragma unroll
    for (int rg = 0; rg < 4; rg++) {
      int r = row0 + w*16 + q*4 + rg;
      float v = acc[t][rg];
      if (bias)   v += bias[c];
      if (relu)   v = fmaxf(v, 0.f);
      if (rowvec) v += rowvec[(size_t)(r >> 10)*DD + c];
      vv[t][rg] = v;
    }
  }

  if (as_out) {  // 4-head score partials over this block's 64 cols
    #pragma unroll
    for (int h = 0; h < 4; h++) {
      float ps[4] = {}, pd[4] = {};
      #pragma unroll
      for (int t = 0; t < 4; t++) {
        int c = col0 + t*16 + mn;
        float av = uS[h*DD + c], dv = uD[h*DD + c];
        #pragma unroll
        for (int rg = 0; rg < 4; rg++) { ps[rg] += vv[t][rg]*av; pd[rg] += vv[t][rg]*dv; }
      }
      #pragma unroll
      for (int rg = 0; rg < 4; rg++) {
        #pragma unroll
        for (int off = 1; off < 16; off <<= 1) {
          ps[rg] += __shfl_xor(ps[rg], off);
          pd[rg] += __shfl_xor(pd[rg], off);
        }
        if (mn == 0) {
          int r = row0 + w*16 + q*4 + rg;
          atomicAdd(&as_out[r*4 + h], ps[rg]);
          atomicAdd(&ad_out[r*4 + h], pd[rg]);
        }
      }
    }
  }

  if (s0b) {  // per-row 2-token dot partials (batch-indexed vectors)
    int b = row0 >> 10;
    float txv[4], exv[4];
    #pragma unroll
    for (int t = 0; t < 4; t++) {
      int c = col0 + t*16 + mn;
      txv[t] = ctx[b*DD + c]; exv[t] = ced[b*DD + c];
    }
    float ss0[4] = {}, ss1[4] = {};
    #pragma unroll
    for (int t = 0; t < 4; t++)
      #pragma unroll
      for (int rg = 0; rg < 4; rg++) { ss0[rg] += vv[t][rg]*txv[t]; ss1[rg] += vv[t][rg]*exv[t]; }
    #pragma unroll
    for (int rg = 0; rg < 4; rg++) {
      #pragma unroll
      for (int off = 1; off < 16; off <<= 1) {
        ss0[rg] += __shfl_xor(ss0[rg], off);
        ss1[rg] += __shfl_xor(ss1[rg], off);
      }
      if (mn == 0) {
        int r = row0 + w*16 + q*4 + rg;
        atomicAdd(&s0b[r], ss0[rg]);
        atomicAdd(&s1b[r], ss1[rg]);
      }
    }
  }

  #pragma unroll
  for (int t = 0; t < 4; t++) {
    int c = col0 + t*16 + mn;
    #pragma unroll
    for (int rg = 0; rg < 4; rg++) {
      int r = row0 + w*16 + q*4 + rg;
      stC(&C[(size_t)r*N + c], vv[t][rg]);
    }
  }
}

// ---------------------------------------------------------------------------
// GAT gather in x-space: agg[i][h*256+d] = (0.25/den_h) * sum_j w^h_ij x[j][d].
// ---------------------------------------------------------------------------
__global__ __launch_bounds__(256) void gat_gather(
    const bf16* __restrict__ x, const float* __restrict__ a_s, const float* __restrict__ a_d,
    const int* __restrict__ cnt, const int* __restrict__ csr,
    bf16* __restrict__ agg)
{
  int i = blockIdx.x, t = threadIdx.x;
  int h = t >> 6, l = t & 63;
  int beg = i*DEGC;
  int deg = cnt[i]; if (deg > DEGC) deg = DEGC;
  __shared__ float sal[4][DEGC];
  __shared__ int   scsr[DEGC];
  float adh = a_d[i*4 + h];
  float mloc = -1e30f;
  for (int idx = l; idx < deg; idx += 64) {
    int sn = csr[beg + idx];
    if (h == 0) scsr[idx] = sn;
    float al = a_s[sn*4 + h] + adh;
    al = al > 0.f ? al : 0.2f*al;
    sal[h][idx] = al;
    mloc = fmaxf(mloc, al);
  }
  float mh = wredmax(mloc);                     // finite: deg >= 1 (self-loop)
  float sloc = 0.f;
  for (int idx = l; idx < deg; idx += 64) {
    float wv = expf(sal[h][idx] - mh);
    sal[h][idx] = wv;
    sloc += wv;
  }
  float inv = 0.25f / wredsum(sloc);            // fold head-mean 1/4 here
  __syncthreads();
  const bf16* xb = x + l*4;
  float a0 = 0.f, a1 = 0.f, a2 = 0.f, a3 = 0.f;
  for (int idx = 0; idx < deg; idx++) {
    int sn = scsr[idx];
    float wv = sal[h][idx];
    uint2 u = *(const uint2*)(xb + (size_t)sn*DD);
    a0 += wv*bf_lo(u.x); a1 += wv*bf_hi(u.x);
    a2 += wv*bf_lo(u.y); a3 += wv*bf_hi(u.y);
  }
  bf16 o[4] = {__float2bfloat16(a0*inv), __float2bfloat16(a1*inv),
               __float2bfloat16(a2*inv), __float2bfloat16(a3*inv)};
  *(uint2*)(agg + (size_t)i*HD + h*DD + l*4) = *(uint2*)o;
}

// ---------------------------------------------------------------------------
// W2 GEMM with comb applied during A-staging:
//   comb[r][c] = x2[r][c] + p0(r)*textf[b][c] + p1(r)*editp[b][c] + mhavec[b][c]
// where p = softmax2(s0[r], s1[r]).  h1 = relu(comb @ W2T^T + bias2) -> bf16.
// ---------------------------------------------------------------------------
__global__ __launch_bounds__(256) void gemm_w2(
    const bf16* __restrict__ A,
    const float* __restrict__ s0b, const float* __restrict__ s1b,
    const float* __restrict__ ctx, const float* __restrict__ ced,
    const float* __restrict__ cmh,
    const bf16* __restrict__ Bt, const float* __restrict__ bias,
    bf16* __restrict__ Cout)
{
  __shared__ __align__(16) bf16 Asl[64*64];
  __shared__ __align__(16) bf16 Bsl[64*64];
  const int N = 512, K = DD;
  int tid = threadIdx.x;
  int w = tid >> 6, lane = tid & 63;
  int q = lane >> 4, mn = lane & 15;
  int row0 = blockIdx.y*64, col0 = blockIdx.x*64;
  int sr = tid >> 3, sc = tid & 7;
  int swc = (sc ^ (sr & 7))*8;
  int b = row0 >> 10;
  int r0a = row0 + sr, r1a = row0 + 32 + sr;
  float p0a, p1a, p0c, p1c;
  {
    float s0 = s0b[r0a], s1 = s1b[r0a];
    float mm = fmaxf(s0, s1);
    float e0 = expf(s0 - mm), e1 = expf(s1 - mm);
    float iv = 1.f/(e0 + e1);
    p0a = e0*iv; p1a = e1*iv;
  }
  {
    float s0 = s0b[r1a], s1 = s1b[r1a];
    float mm = fmaxf(s0, s1);
    float e0 = expf(s0 - mm), e1 = expf(s1 - mm);
    float iv = 1.f/(e0 + e1);
    p0c = e0*iv; p1c = e1*iv;
  }
  floatx4 acc[4];
  #pragma unroll
  for (int t = 0; t < 4; t++) acc[t] = (floatx4){0.f, 0.f, 0.f, 0.f};

  for (int k0 = 0; k0 < K; k0 += 64) {
    int kc = k0 + sc*8;
    float4 t0 = *(const float4*)(ctx + b*DD + kc);
    float4 t1 = *(const float4*)(ctx + b*DD + kc + 4);
    float4 e0v = *(const float4*)(ced + b*DD + kc);
    float4 e1v = *(const float4*)(ced + b*DD + kc + 4);
    float4 m0 = *(const float4*)(cmh + b*DD + kc);
    float4 m1 = *(const float4*)(cmh + b*DD + kc + 4);
    uint4 ua = *(const uint4*)(A + (size_t)r0a*DD + kc);
    uint4 ub = *(const uint4*)(A + (size_t)r1a*DD + kc);
    float4 fa0 = make_float4(bf_lo(ua.x), bf_hi(ua.x), bf_lo(ua.y), bf_hi(ua.y));
    float4 fa1 = make_float4(bf_lo(ua.z), bf_hi(ua.z), bf_lo(ua.w), bf_hi(ua.w));
    float4 fb0 = make_float4(bf_lo(ub.x), bf_hi(ub.x), bf_lo(ub.y), bf_hi(ub.y));
    float4 fb1 = make_float4(bf_lo(ub.z), bf_hi(ub.z), bf_lo(ub.w), bf_hi(ub.w));
    fa0 = combf(fa0, t0, e0v, m0, p0a, p1a);
    fa1 = combf(fa1, t1, e1v, m1, p0a, p1a);
    fb0 = combf(fb0, t0, e0v, m0, p0c, p1c);
    fb1 = combf(fb1, t1, e1v, m1, p0c, p1c);
    uint4 b0 = *(const uint4*)(Bt + (size_t)(col0 + sr)*K      + k0 + sc*8);
    uint4 b1 = *(const uint4*)(Bt + (size_t)(col0 + 32 + sr)*K + k0 + sc*8);
    __syncthreads();
    *(uint4*)&Asl[sr*64 + swc]        = pk8(fa0, fa1);
    *(uint4*)&Asl[(sr + 32)*64 + swc] = pk8(fb0, fb1);
    *(uint4*)&Bsl[sr*64 + swc]        = b0;
    *(uint4*)&Bsl[(sr + 32)*64 + swc] = b1;
    __syncthreads();
    #pragma unroll
    for (int kk = 0; kk < 64; kk += 32) {
      int colk = (kk + q*8) ^ ((mn & 7) << 3);
      short8 af = *(const short8*)&Asl[(w*16 + mn)*64 + colk];
      #pragma unroll
      for (int t = 0; t < 4; t++) {
        short8 bfr = *(const short8*)&Bsl[(t*16 + mn)*64 + colk];
        acc[t] = __builtin_amdgcn_mfma_f32_16x16x32_bf16(af, bfr, acc[t], 0, 0, 0);
      }
    }
  }
  #pragma unroll
  for (int t = 0; t < 4; t++) {
    #pragma unroll
    for (int rg = 0; rg < 4; rg++) {
      int r = row0 + w*16 + q*4 + rg;
      int c = col0 + t*16 + mn;
      float v = fmaxf(acc[t][rg] + bias[c], 0.f);
      Cout[(size_t)r*N + c] = __float2bfloat16(v);
    }
  }
}

// ---------------------------------------------------------------------------
// final-head GEMM (K=512, N=64, block-diag Wd) + fused per-row softmax.
// ---------------------------------------------------------------------------
__global__ __launch_bounds__(256) void gemm_fin(
    const bf16* __restrict__ A, const bf16* __restrict__ Bt,
    const float* __restrict__ bias, float* __restrict__ out)
{
  __shared__ __align__(16) bf16 Asl[64*64];
  __shared__ __align__(16) bf16 Bsl[64*64];
  const int K = 512;
  int tid = threadIdx.x;
  int w = tid >> 6, lane = tid & 63;
  int q = lane >> 4, mn = lane & 15;
  int row0 = blockIdx.x*64;
  int sr = tid >> 3, sc = tid & 7;
  int swc = (sc ^ (sr & 7))*8;
  floatx4 acc[4];
  #pragma unroll
  for (int t = 0; t < 4; t++) acc[t] = (floatx4){0.f, 0.f, 0.f, 0.f};
  for (int k0 = 0; k0 < K; k0 += 64) {
    uint4 a0 = *(const uint4*)(A  + (size_t)(row0 + sr)*K      + k0 + sc*8);
    uint4 a1 = *(const uint4*)(A  + (size_t)(row0 + 32 + sr)*K + k0 + sc*8);
    uint4 b0 = *(const uint4*)(Bt + (size_t)sr*K      + k0 + sc*8);
    uint4 b1 = *(const uint4*)(Bt + (size_t)(32 + sr)*K + k0 + sc*8);
    __syncthreads();
    *(uint4*)&Asl[sr*64 + swc]        = a0;
    *(uint4*)&Asl[(sr + 32)*64 + swc] = a1;
    *(uint4*)&Bsl[sr*64 + swc]        = b0;
    *(uint4*)&Bsl[(sr + 32)*64 + swc] = b1;
    __syncthreads();
    #pragma unroll
    for (int kk = 0; kk < 64; kk += 32) {
      int colk = (kk + q*8) ^ ((mn & 7) << 3);
      short8 af = *(const short8*)&Asl[(w*16 + mn)*64 + colk];
      #pragma unroll
      for (int t = 0; t < 4; t++) {
        short8 bfr = *(const short8*)&Bsl[(t*16 + mn)*64 + colk];
        acc[t] = __builtin_amdgcn_mfma_f32_16x16x32_bf16(af, bfr, acc[t], 0, 0, 0);
      }
    }
  }
  #pragma unroll
  for (int rg = 0; rg < 4; rg++) {
    int r = row0 + w*16 + q*4 + rg;
    float mx = -1e30f;
    #pragma unroll
    for (int t = 0; t < 4; t++) {
      int c = t*16 + mn;
      float val = acc[t][rg] + bias[c];
      if (c >= 3 && c < 23) mx = fmaxf(mx, val);
    }
    #pragma unroll
    for (int off = 1; off < 16; off <<= 1) mx = fmaxf(mx, __shfl_xor(mx, off));
    float sum = 0.f;
    #pragma unroll
    for (int t = 0; t < 4; t++) {
      int c = t*16 + mn;
      float val = acc[t][rg] + bias[c];
      if (c >= 3 && c < 23) sum += expf(val - mx);
    }
    #pragma unroll
    for (int off = 1; off < 16; off <<= 1) sum += __shfl_xor(sum, off);
    float inv = 1.f / sum;
    #pragma unroll
    for (int t = 0; t < 2; t++) {
      int c = t*16 + mn;
      float val = acc[t][rg] + bias[c];
      if (c < 3) out[(size_t)r*3 + c] = val;
      else if (c < 23) out[24576 + (size_t)r*20 + (c - 3)] = expf(val - mx)*inv;
    }
  }
}

// ---------------------------------------------------------------------------
extern "C" void kernel_launch(void* const* d_in, const int* in_sizes, int n_in,
                              void* d_out, int out_size, void* d_ws, size_t ws_size,
                              hipStream_t stream)
{
  (void)in_sizes; (void)n_in; (void)out_size; (void)ws_size;
  const float* structure_emb = (const float*)d_in[0];
  const float* text_emb      = (const float*)d_in[1];
  const float* edit_emb      = (const float*)d_in[3];
  const float* ws_w    = (const float*)d_in[4];
  const float* bs_b    = (const float*)d_in[5];
  const float* wt_w    = (const float*)d_in[6];
  const float* bt_b    = (const float*)d_in[7];
  const float* we_w    = (const float*)d_in[8];
  const float* be_b    = (const float*)d_in[9];
  const float* wp_w    = (const float*)d_in[10];
  const float* bp_b    = (const float*)d_in[11];
  const float* g1_lin  = (const float*)d_in[12];
  const float* g1_as   = (const float*)d_in[13];
  const float* g1_ad   = (const float*)d_in[14];
  const float* g1_b    = (const float*)d_in[15];
  const float* g2_lin  = (const float*)d_in[16];
  const float* g2_as   = (const float*)d_in[17];
  const float* g2_ad   = (const float*)d_in[18];
  const float* g2_b    = (const float*)d_in[19];
  const float* mha_iw  = (const float*)d_in[20];
  const float* mha_ib  = (const float*)d_in[21];
  const float* mha_ow  = (const float*)d_in[22];
  const float* mha_ob  = (const float*)d_in[23];
  const float* cw1     = (const float*)d_in[24];
  const float* cb1     = (const float*)d_in[25];
  const float* cw2     = (const float*)d_in[26];
  const float* cb2     = (const float*)d_in[27];
  const float* aw1     = (const float*)d_in[28];
  const float* ab1     = (const float*)d_in[29];
  const float* aw2     = (const float*)d_in[30];
  const float* ab2     = (const float*)d_in[31];
  const int*  edge_index = (const int*)d_in[32];
  float* out = (float*)d_out;

  // --- workspace layout (~27.9 MB, proven envelope) ---
  char* p = (char*)d_ws;
  // 16 MB big region, time-multiplexed: agg (16MB) -> h1b (8MB)
  bf16*  aggb  = (bf16*)p;
  bf16*  h1b   = (bf16*)p;
  p += 16777216;
  bf16* bufB = (bf16*)p; p += 4194304;   // [8192][256] bf16: x0 -> x1e -> x2
  bf16* g1R  = (bf16*)p; p += 524288;    // [256][1024] per-head transposed g1_lin
  bf16* g2R  = (bf16*)p; p += 524288;
  bf16* W2T  = (bf16*)p; p += 262144;    // [512][256]: cw1T ++ aw1T
  bf16* WfT  = (bf16*)p; p += 393216;    // [256][768]
  bf16* WdT  = (bf16*)p; p += 65536;     // [64][512] block-diag final weight
  float* Wcv = (float*)p; p += 262144;   // [256][256] fp32 collapsed MHA weight
  float* bcv = (float*)p; p += 1024;
  float* textf  = (float*)p; p += 8192;
  float* editp  = (float*)p; p += 8192;
  float* mhavec = (float*)p; p += 8192;
  float* cvec   = (float*)p; p += 8192;
  float* bias2  = (float*)p; p += 2048;
  float* bias23 = (float*)p; p += 256;
  float* u1s = (float*)p; p += 4096;     // [4][256] score vectors
  float* u1d = (float*)p; p += 4096;
  float* u2s = (float*)p; p += 4096;
  float* u2d = (float*)p; p += 4096;
  float* a_s1   = (float*)p; p += 131072;  // zz block: a_s1,a_d1,a_s2,a_d2
  float* a_d1   = (float*)p; p += 131072;
  float* a_s2   = (float*)p; p += 131072;
  float* a_d2   = (float*)p; p += 131072;
  float* s0b    = (float*)p; p += 32768;   // [8192] comb dot partials
  float* s1b    = (float*)p; p += 32768;
  int* counts = (int*)p; p += 32768;
  int* csr    = (int*)p; p += BN*DEGC*4;   // padded CSR, 4 MB

  prep1<<<960, 256, 0, stream>>>(
      text_emb, edit_emb, wt_w, bt_b, we_w, be_b, textf, editp,
      ws_w, wp_w, WfT,
      mha_iw, mha_ib, mha_ow, mha_ob, Wcv, bcv,
      g1_lin, g1R, g2_lin, g2R, cw1, aw1, W2T,
      cw2, cb2, aw2, ab2, WdT, bias23,
      counts, csr, a_s1, s0b, s1b, cb1, ab1, bias2);
  prep2<<<592, 256, 0, stream>>>(
      textf, editp, Wcv, bcv, mhavec, bs_b, wp_w, bp_b, cvec,
      g1R, g2R, g1_as, g1_ad, g2_as, g2_ad, u1s, u1d, u2s, u2d,
      edge_index, counts, csr);

  // x0 = bf16(semb) @ Wfull + cvec[batch] -> bufB; fused layer-1 scores
  gemm_x0f<<<dim3(DD/64, BN/64), 256, 0, stream>>>(
      structure_emb, WfT, bufB, cvec, u1s, u1d, a_s1, a_d1);

  // GAT layer 1: gather in x-space -> agg1; x1e = relu(agg1@g1R + b1) + edit
  gat_gather<<<BN, 256, 0, stream>>>(bufB, a_s1, a_d1, counts, csr, aggb);
  gemm_mfma<bf16><<<dim3(DD/64, BN/64), 256, 0, stream>>>(
      aggb, g1R, bufB, BN, DD, HD, g1_b, 1, editp,
      u2s, u2d, a_s2, a_d2, nullptr, nullptr, nullptr, nullptr);

  // GAT layer 2: gather -> agg2; x2 = relu(agg2@g2R + b2) -> bufB; comb dots
  gat_gather<<<BN, 256, 0, stream>>>(bufB, a_s2, a_d2, counts, csr, aggb);
  gemm_mfma<bf16><<<dim3(DD/64, BN/64), 256, 0, stream>>>(
      aggb, g2R, bufB, BN, DD, HD, g2_b, 1, nullptr,
      nullptr, nullptr, nullptr, nullptr, textf, editp, s0b, s1b);

  // W2 head: comb in staging -> h1b (aggb dead by now)
  gemm_w2<<<dim3(8, BN/64), 256, 0, stream>>>(
      bufB, s0b, s1b, textf, editp, mhavec, W2T, bias2, h1b);

  // final projection + fused softmax -> d_out
  gemm_fin<<<BN/64, 256, 0, stream>>>(h1b, WdT, bias23, out);
}